// Round 8
// baseline (1657.726 us; speedup 1.0000x reference)
//
#include <hip/hip_runtime.h>
#include <stdint.h>

#define T_STEPS 1024
#define BATCH   512
#define INF     64
#define HID     128
#define OUTF    2

// d_out[0..1023] = z_sum [512][2], d_out[1024] = spikerate.
// During the seq kernel, d_out[1024] (reinterpreted as uint) is the global
// spike counter (exact integer atomics -> deterministic); finalize converts.

__global__ void zero_kernel(unsigned int* __restrict__ counter)
{
    *counter = 0u;
}

// grid 256 x 256 threads; block = 2 batch rows (g = tid>>7), neuron h = tid&127.
// Semantics this round (NEP-50 promotion hypothesis): numpy reference with
// DT materialized as float64 =>
//   - v, i state and all elementwise ops: float64, coefficients
//     dtm = 0.001(f64)*tau_mem(f32->f64), dts likewise; separate mul/add
//     roundings (contract off)
//   - inp = x_t @ W_in.T      : f32 sgemm, class-A (seq-k single-acc FMA)
//   - pre = inp @ cWi.T       : f32 sgemm, class-A
//   - rec = z(f64) @ Wrec.T   : f64 dgemm == exact sum of f32 columns
//   - z f64 in {0.0,1.0}; v_new = (1-z)*v_dec + z*0 exact
__global__ __launch_bounds__(256, 1)
void snn_seq(const float* __restrict__ x,        // [T][B][64]
             const float* __restrict__ W_in,     // [128][64]
             const float* __restrict__ cWi,      // [128][128]
             const float* __restrict__ Wrec,     // [128][128]
             const float* __restrict__ W_out,    // [2][128]
             const float* __restrict__ b_out,    // [2]
             const float* __restrict__ v_th,     // [128]
             const float* __restrict__ v_leak1,  // [1]
             const float* __restrict__ v_reset,  // [128]
             const float* __restrict__ tau_mem,  // [128]
             const float* __restrict__ tau_syn,  // [128]
             float* __restrict__ out,            // [512][2] + [1]
             unsigned int* __restrict__ counter)
{
    #pragma clang fp contract(off)

    extern __shared__ char smem[];
    float* Wrec_T  = (float*)smem;                 // [128][128]: Wrec_T[j][h] = Wrec[h][j]
    float* x_lds   = Wrec_T + HID * HID;           // [2 buf][2 grp][64]
    float* inp_lds = x_lds + 2 * 2 * INF;          // [2 grp][128] (f32 inp)
    unsigned long long* mask_lds =
        (unsigned long long*)(inp_lds + 2 * HID);  // [2 buf][2 grp][2 half]

    const int tid = threadIdx.x;
    const int g   = tid >> 7;          // batch row within block
    const int h   = tid & (HID - 1);   // neuron index
    const int b   = blockIdx.x * 2 + g;
    const int wv  = (tid >> 6) & 1;    // wave half within group

    // ---- stage Wrec transposed into LDS (lane-consecutive reads later)
    for (int idx = tid; idx < HID * HID; idx += 256)
        Wrec_T[idx] = Wrec[(idx & (HID - 1)) * HID + (idx >> 7)];

    // ---- per-neuron coefficients: float64 (promotion semantics)
    const double vth   = (double)v_th[h];      // 1.0 exact
    const double vleak = (double)v_leak1[0];   // 0.0
    const double vrst  = (double)v_reset[h];   // 0.0
    const double dtm   = 0.001 * (double)tau_mem[h];   // f64(0.001)*100 -> 0.1(f64)
    const double dts   = 0.001 * (double)tau_syn[h];   // -> 0.2(f64)

    // ---- weight rows in registers (f32): W_in[h][0..63], cWi[h][0..127]
    float win[INF];
    #pragma unroll
    for (int q = 0; q < INF / 4; ++q) {
        float4 w4 = ((const float4*)(W_in + h * INF))[q];
        win[4 * q + 0] = w4.x; win[4 * q + 1] = w4.y;
        win[4 * q + 2] = w4.z; win[4 * q + 3] = w4.w;
    }
    float cw[HID];
    #pragma unroll
    for (int q = 0; q < HID / 4; ++q) {
        float4 w4 = ((const float4*)(cWi + h * HID))[q];
        cw[4 * q + 0] = w4.x; cw[4 * q + 1] = w4.y;
        cw[4 * q + 2] = w4.z; cw[4 * q + 3] = w4.w;
    }

    // ---- init: masks(buf0)=0 (z0=0), x(t=0) into buf0
    if (tid < 8) mask_lds[tid] = 0ull;
    if (h < INF) x_lds[g * INF + h] = x[(size_t)b * INF + h];
    __syncthreads();

    double v = 0.0, cur = 0.0;
    int cnt = 0;

    for (int t = 0; t < T_STEPS; ++t) {
        const int buf  = t & 1;
        const int nbuf = buf ^ 1;

        // ---- stage1 (f32 class-A): inp[h] = seq-k single-acc FMA chain
        float s = 0.f;
        const float* xr = x_lds + (buf * 2 + g) * INF;
        #pragma unroll
        for (int k = 0; k < INF; k += 4) {
            float4 x4 = *(const float4*)(xr + k);
            s = fmaf(x4.x, win[k + 0], s);
            s = fmaf(x4.y, win[k + 1], s);
            s = fmaf(x4.z, win[k + 2], s);
            s = fmaf(x4.w, win[k + 3], s);
        }
        inp_lds[g * HID + h] = s;

        // prefetch next x tile into the other buffer
        if (h < INF) {
            int tn = (t + 1 < T_STEPS) ? t + 1 : t;
            x_lds[(nbuf * 2 + g) * INF + h] = x[((size_t)tn * BATCH + b) * INF + h];
        }
        // previous-step spike masks for this row
        unsigned long long m0 = mask_lds[buf * 4 + g * 2 + 0];
        unsigned long long m1 = mask_lds[buf * 4 + g * 2 + 1];

        __syncthreads();   // inp_lds ready

        // ---- rec (f64 dgemm == exact): sparse adds, 4 pipelined chains
        double r0 = 0.0, r1 = 0.0, r2 = 0.0, r3 = 0.0;
        {
            unsigned int mm;
            mm = (unsigned int)m0;
            while (mm) { int j = __builtin_ctz(mm); mm &= mm - 1; r0 += (double)Wrec_T[j * HID + h]; }
            mm = (unsigned int)(m0 >> 32);
            while (mm) { int j = __builtin_ctz(mm); mm &= mm - 1; r1 += (double)Wrec_T[(j + 32) * HID + h]; }
            mm = (unsigned int)m1;
            while (mm) { int j = __builtin_ctz(mm); mm &= mm - 1; r2 += (double)Wrec_T[(j + 64) * HID + h]; }
            mm = (unsigned int)(m1 >> 32);
            while (mm) { int j = __builtin_ctz(mm); mm &= mm - 1; r3 += (double)Wrec_T[(j + 96) * HID + h]; }
        }
        double rec = (r0 + r1) + (r2 + r3);

        // ---- stage2 (f32 class-A): pre = seq-j single-acc FMA chain over inp
        float pre = 0.f;
        const float* ir = inp_lds + g * HID;
        #pragma unroll
        for (int j = 0; j < HID; j += 4) {
            float4 i4 = *(const float4*)(ir + j);
            pre = fmaf(i4.x, cw[j + 0], pre);
            pre = fmaf(i4.y, cw[j + 1], pre);
            pre = fmaf(i4.z, cw[j + 2], pre);
            pre = fmaf(i4.w, cw[j + 3], pre);
        }

        // ---- LIF update: float64, np op order, separate roundings
        double v_dec = v + dtm * ((vleak - v) + cur);
        double i_dec = cur - dts * cur;
        bool   z     = (v_dec - vth) > 0.0;
        v   = z ? vrst : v_dec;                    // (1-z)*v_dec + z*0, exact
        cur = (i_dec + (double)pre) + rec;         // left-assoc, f64
        cnt += z ? 1 : 0;

        unsigned long long bal = __ballot(z);
        if ((tid & 63) == 0) mask_lds[nbuf * 4 + g * 2 + wv] = bal;
        __syncthreads();   // masks/x ready; inp_lds consumers done
    }

    // ---- epilogue: z_sum[b] = (sum_t z)@W_out.T + T*b_out ; global spike count
    float* cnt_lds = inp_lds;          // reuse (256 floats)
    cnt_lds[tid] = (float)cnt;         // counts <= 1024: exact
    __syncthreads();
    if (tid < 4) {
        int go = tid >> 1, oo = tid & 1;
        double sAcc = 0.0;
        for (int hh = 0; hh < HID; ++hh)
            sAcc += (double)cnt_lds[go * HID + hh] * (double)W_out[oo * HID + hh];
        out[(size_t)(blockIdx.x * 2 + go) * OUTF + oo] =
            (float)(sAcc + 1024.0 * (double)b_out[oo]);
    }
    if (tid == 0) {
        unsigned int tot = 0;
        for (int k2 = 0; k2 < 256; ++k2) tot += (unsigned int)cnt_lds[k2];
        atomicAdd(counter, tot);
    }
}

__global__ void finalize_kernel(float* __restrict__ out)
{
    unsigned int c = ((const unsigned int*)out)[BATCH * OUTF];
    out[BATCH * OUTF] = (float)c * 0x1p-26f;   // / (1024*512*128), exact pow2
}

extern "C" void kernel_launch(void* const* d_in, const int* in_sizes, int n_in,
                              void* d_out, int out_size, void* d_ws, size_t ws_size,
                              hipStream_t stream) {
    (void)in_sizes; (void)n_in; (void)d_ws; (void)ws_size; (void)out_size;

    const float* x       = (const float*)d_in[0];
    const float* W_in    = (const float*)d_in[1];
    const float* cWi     = (const float*)d_in[2];
    const float* cWr     = (const float*)d_in[3];
    const float* W_out   = (const float*)d_in[4];
    const float* b_out   = (const float*)d_in[5];
    // d_in[6] = alpha (unused in forward)
    const float* v_th    = (const float*)d_in[7];
    const float* v_leak  = (const float*)d_in[8];
    const float* v_reset = (const float*)d_in[9];
    const float* tau_mem = (const float*)d_in[10];
    const float* tau_syn = (const float*)d_in[11];
    float* out = (float*)d_out;
    unsigned int* counter = (unsigned int*)out + BATCH * OUTF;

    zero_kernel<<<1, 1, 0, stream>>>(counter);

    const size_t lds_bytes =
        (size_t)(HID * HID + 2 * 2 * INF + 2 * HID) * sizeof(float)
        + 2 * 2 * 2 * sizeof(unsigned long long);
    snn_seq<<<dim3(256), dim3(256), lds_bytes, stream>>>(
        x, W_in, cWi, cWr, W_out, b_out, v_th, v_leak, v_reset,
        tau_mem, tau_syn, out, counter);

    finalize_kernel<<<1, 1, 0, stream>>>(out);
}